// Round 12
// baseline (435.099 us; speedup 1.0000x reference)
//
#include <hip/hip_runtime.h>

#define NN 20000
#define NE 40000
#define NGR 1000
#define KH 2                      // K-split for k_msg
#define WTF_BIAS 524288           // u16 offset of bias frags in WtF

typedef unsigned short u16;
typedef u16 u16x8 __attribute__((ext_vector_type(8)));
typedef __bf16 bf16x8 __attribute__((ext_vector_type(8)));
typedef float f32x4 __attribute__((ext_vector_type(4)));

union U8 { u16x8 u; bf16x8 b; };

__device__ __forceinline__ u16 f2bf(float f) {
    union { float f; unsigned u; } v; v.f = f;
    unsigned r = v.u + 0x7FFF + ((v.u >> 16) & 1);   // RNE
    return (u16)(r >> 16);
}
__device__ __forceinline__ float bf2f(u16 h) {
    union { unsigned u; float f; } v; v.u = ((unsigned)h) << 16;
    return v.f;
}
__device__ __forceinline__ float sigmoidf(float x) { return 1.f / (1.f + __expf(-x)); }

// async global->LDS, 16B per lane; LDS dest = wave-uniform base + lane*16
__device__ __forceinline__ void gl_lds16(const u16* g, u16* l) {
    __builtin_amdgcn_global_load_lds(
        (const __attribute__((address_space(1))) void*)g,
        (__attribute__((address_space(3))) void*)l, 16, 0, 0);
}

// ---------------- degree count ----------------
__global__ __launch_bounds__(256) void k_cnt(const int* __restrict__ ei, int* __restrict__ cnt)
{
    for (int e = blockIdx.x * 256 + threadIdx.x; e < NE; e += gridDim.x * 256)
        atomicAdd(&cnt[ei[NE + e]], 1);
}

// ---------------- exclusive prefix over cnt -> rowptr[NN+1], one block ----------
__global__ __launch_bounds__(1024) void k_scan(const int* __restrict__ cnt,
                                               int* __restrict__ rowptr)
{
    __shared__ int ps[1024];
    int t = threadIdx.x;
    int base = t * 20;
    int loc[20];
    int s = 0;
#pragma unroll
    for (int i = 0; i < 20; ++i) {
        int idx = base + i;
        loc[i] = s;
        s += (idx < NN) ? cnt[idx] : 0;
    }
    ps[t] = s;
    __syncthreads();
    for (int off = 1; off < 1024; off <<= 1) {
        int v = (t >= off) ? ps[t - off] : 0;
        __syncthreads();
        ps[t] += v;
        __syncthreads();
    }
    int ex = (t > 0) ? ps[t - 1] : 0;
#pragma unroll
    for (int i = 0; i < 20; ++i) {
        int idx = base + i;
        if (idx < NN) rowptr[idx] = ex + loc[i];
    }
    if (t == 1023) rowptr[NN] = ps[1023];
}

// -------- scatter: epos[e] = dst-sorted slot; srcs/dsts[slot] ------------------
__global__ __launch_bounds__(256) void k_scatter(const int* __restrict__ ei,
    const int* __restrict__ rowptr, int* __restrict__ cur,
    int* __restrict__ epos, int* __restrict__ srcs, int* __restrict__ dsts)
{
    for (int e = blockIdx.x * 256 + threadIdx.x; e < NE; e += gridDim.x * 256) {
        int d = ei[NE + e];
        int pos = rowptr[d] + atomicAdd(&cur[d], 1);
        epos[e] = pos;
        srcs[pos] = ei[e];
        dsts[pos] = d;
    }
}

// ============ fused one-time preamble, 992 blocks, role by blockIdx range ======
__global__ __launch_bounds__(256) void k_pre(
    const float* __restrict__ x, const float* __restrict__ ea,
    const int* __restrict__ batch, const int* __restrict__ epos,
    const float* __restrict__ W0, const float* __restrict__ b0,
    const float* __restrict__ We1, const float* __restrict__ be1,
    const float* __restrict__ We2, const float* __restrict__ be2,
    const float* __restrict__ W_ih, const float* __restrict__ W_hh,
    const float* __restrict__ W_ihl, const float* __restrict__ W_hhl,
    const float* __restrict__ W1,
    float* __restrict__ h, u16* __restrict__ outb, u16* __restrict__ h1,
    u16* __restrict__ WtF, int* __restrict__ gstart, int* __restrict__ gend,
    u16* __restrict__ WgF,
    float* __restrict__ WTihl, float* __restrict__ WThhl, float* __restrict__ WT1)
{
    const int b = blockIdx.x;
    const int t = threadIdx.x;

    if (b < 64) {                 // WgF frag-major GRU weights + transposes (90112)
        for (int idx = b * 256 + t; idx < 90112; idx += 64 * 256) {
            int i = idx;
            if (i < 32768) {      // WgF: [ks 0..3][nt 0..15][lane 0..63][j 0..7]
                int j = i & 7, lane = (i >> 3) & 63;
                int nt = (i >> 9) & 15, ks = i >> 13;
                int o = nt * 16 + (lane & 15);
                int k = ks * 32 + (lane >> 4) * 8 + j;
                float v;
                if (o < 128)      v = (k < 64) ? W_ih[o * 64 + k] : W_hh[o * 64 + k - 64];
                else if (o < 192) v = (k < 64) ? W_ih[o * 64 + k] : 0.f;
                else              v = (k >= 64) ? W_hh[(o - 64) * 64 + k - 64] : 0.f;
                WgF[i] = f2bf(v);
                continue;
            }
            i -= 32768;
            if (i < 32768) { WTihl[i] = W_ihl[(i % 256) * 128 + i / 256]; continue; }
            i -= 32768;
            if (i < 16384) { WThhl[i] = W_hhl[(i % 256) * 64 + i / 256]; continue; }
            i -= 16384;
            WT1[i] = W1[(i % 64) * 128 + i / 64];
        }
        return;
    }
    if (b < 320) {                                   // lin0, 1024 waves grid-stride
        int wv = (b - 64) * 4 + (t >> 6);
        int lane = t & 63;
        float w0r[32];
#pragma unroll
        for (int f = 0; f < 32; ++f) w0r[f] = W0[lane * 32 + f];
        float b0v = b0[lane];
        for (int n = wv; n < NN; n += 1024) {
            float xv = (lane < 32) ? x[n * 32 + lane] : 0.f;
            float acc = b0v;
#pragma unroll
            for (int f = 0; f < 32; ++f) acc += __shfl(xv, f, 64) * w0r[f];
            float rv = fmaxf(acc, 0.f);
            h[n * 64 + lane] = rv;
            outb[n * 64 + lane] = f2bf(rv);
        }
        return;
    }
    if (b < 832) {                                   // edge MLP -> dst-sorted h1
        for (int idx = (b - 320) * 256 + t; idx < NE * 128; idx += 512 * 256) {
            int e = idx >> 7, k = idx & 127;
            float acc = be1[k];
#pragma unroll
            for (int j = 0; j < 5; ++j)
                acc += ea[e * 5 + j] * We1[k * 5 + j];
            h1[(size_t)epos[e] * 128 + k] = f2bf(fmaxf(acc, 0.f));
        }
        return;
    }
    if (b < 960) {                                   // WtF: frag-major B for k_msg
        for (int idx = (b - 832) * 256 + t; idx < WTF_BIAS + 4096; idx += 128 * 256) {
            float v;
            if (idx < WTF_BIAS) {
                int j = idx & 7, lane = (idx >> 3) & 63;
                int nt = (idx >> 9) & 3, s4 = (idx >> 11) & 3, ch = idx >> 13;
                int o = nt * 16 + (lane & 15);
                int k = s4 * 32 + (lane >> 4) * 8 + j;
                v = We2[(size_t)(ch * 64 + o) * 128 + k];
            } else {
                int bx = idx - WTF_BIAS;
                int j = bx & 7, lane = (bx >> 3) & 63;
                int nt = (bx >> 9) & 3, sb = bx >> 11;
                int o = nt * 16 + (lane & 15);
                int i = sb * 32 + (lane >> 4) * 8 + j;
                v = be2[i * 64 + o];
            }
            WtF[idx] = f2bf(v);
        }
        return;
    }
    {                                                // graph ranges (batch sorted)
        for (int idx = (b - 960) * 256 + t; idx < NN; idx += 32 * 256) {
            int bg = batch[idx];
            if (idx == 0 || batch[idx - 1] != bg) gstart[bg] = idx;
            if (idx == NN - 1 || batch[idx + 1] != bg) gend[bg] = idx + 1;
        }
    }
}

// ---------------- message GEMM + fused scatter-reduce -----------------------------
// R12: grid-supply fix. R11 showed LDS allowed 3+ blocks/CU but the grid (628)
// only supplied 2.45/CU -- occupancy stuck at 21%. Split output 4-way (z=0..3,
// one 16-col nt-quarter per block): grid (157,2,4)=1256 ~ 4.9 blocks/CU.
// Chosen over KH=4 because z-quarters own disjoint cols -> NO extra atomics;
// total WtF L2 traffic unchanged (1256 x 128KB = 628 x 256KB); B-reuse per LDS
// byte preserved (4KB feeds 16 MFMA/wave, same ratio). LDS 24KB (svT 16 + LB 8)
// -> 4-5 blocks/CU fit; VGPR ~84. Schedule = R9's proven counted-vmcnt dual
// barrier, with vmcnt(1) (one stage load/wave in flight).
__global__ __launch_bounds__(256, 4) void k_msg(
    const u16* __restrict__ outb, const u16* __restrict__ h1,
    const u16* __restrict__ WtF, const int* __restrict__ srcs,
    const int* __restrict__ dsts, float* __restrict__ agg)
{
    __shared__ __align__(16) u16 svT[32 * 256];  // [cl][row ^ ((cl>>3)<<4)], 16 KB
    __shared__ __align__(16) u16 LB[2 * 2048];   // B stage, 2 x (4 frags x 512 u16)
    const int t = threadIdx.x;
    const int eb0 = blockIdx.x * 256;
    const int kh = blockIdx.y;                   // channel half: ch = kh*32 + cl
    const int ntg = blockIdx.z;                  // output quarter: cols ntg*16..+15

#pragma unroll
    for (int r = 0; r < 4; ++r) {                // gather out[srcs] kh-half -> svT
        int cid = t + 256 * r;                   // 0..1023
        int row = cid >> 2, c4 = cid & 3;        // 256 rows x 4 chunks of 8 dims
        int e = eb0 + row;
        u16x8 v = {};
        if (e < NE) {
            int s = srcs[e];
            v = *(const u16x8*)(outb + (size_t)s * 64 + kh * 32 + c4 * 8);
        }
        int rs = row ^ (c4 << 4);                // swz = (cl>>3)<<4, cl = c4*8+j
#pragma unroll
        for (int j = 0; j < 8; ++j)
            svT[(c4 * 8 + j) * 256 + rs] = v[j];
    }

    const int lane = t & 63, w = t >> 6, r16 = lane & 15, q = lane >> 4;
    const int w64 = w * 64;

    // static A-fragments: h1 rows, 64 edges/wave, reused across all channels
    u16x8 h1r[4][4];
#pragma unroll
    for (int sub = 0; sub < 4; ++sub) {
        int e = eb0 + w64 + sub * 16 + r16;
        if (e >= NE) e = NE - 1;                 // contribution zeroed via sv=0
        const u16* hp = h1 + (size_t)e * 128 + q * 8;
#pragma unroll
        for (int s4 = 0; s4 < 4; ++s4)
            h1r[sub][s4] = *(const u16x8*)(hp + s4 * 32);
    }

    f32x4 acc[4];
    const f32x4 z4 = {0.f, 0.f, 0.f, 0.f};
#pragma unroll
    for (int sub = 0; sub < 4; ++sub) acc[sub] = z4;

    const int chBase = kh * 32;
    u16* lb0 = &LB[0];
    u16* lb1 = &LB[2048];

    // stage channel ch's nt-quarter (4 frags x 1KB): wave w loads frag s4=w
    auto STAGE = [&](u16* lb, int ch) {
        const u16* g = WtF + (size_t)ch * 8192 + w * 2048 + ntg * 512 + lane * 8;
        gl_lds16(g, lb + w * 512);
    };
    auto SCALE = [&](f32x4 (&P)[4], int cl) {    // cl = local channel [0,32)
        int swz = (cl >> 3) << 4;
#pragma unroll
        for (int sub = 0; sub < 4; ++sub) {
            int mb = (w64 + sub * 16 + q * 4) ^ swz;
            uint2 rv = *(const uint2*)&svT[cl * 256 + mb];
            union { unsigned u; float f; } c0, c1, c2, c3;
            c0.u = rv.x << 16; c1.u = rv.x & 0xffff0000u;
            c2.u = rv.y << 16; c3.u = rv.y & 0xffff0000u;
            acc[sub][0] += c0.f * P[sub][0];
            acc[sub][1] += c1.f * P[sub][1];
            acc[sub][2] += c2.f * P[sub][2];
            acc[sub][3] += c3.f * P[sub][3];
        }
    };

    STAGE(lb0, chBase);                          // prefetch channel 0 (1 load/wave)

#pragma unroll 1
    for (int cc = 0; cc < 32; ++cc) {
        u16* cur = (cc & 1) ? lb1 : lb0;
        u16* nxt = (cc & 1) ? lb0 : lb1;
        if (cc < 31) {
            STAGE(nxt, chBase + cc + 1);         // issue next-channel load
            // cur's stage load (older) must land; the just-issued stays in flight
            asm volatile("s_waitcnt vmcnt(1) lgkmcnt(0)" ::: "memory");
        } else {
            asm volatile("s_waitcnt vmcnt(0) lgkmcnt(0)" ::: "memory");
        }
        __builtin_amdgcn_s_barrier();            // B1: cur buffer fully written
        asm volatile("" ::: "memory");

        U8 bv[4];                                // shared B frags: LDS -> regs
#pragma unroll
        for (int f = 0; f < 4; ++f)
            bv[f].u = *(const u16x8*)(cur + f * 512 + lane * 8);

        if (cc < 31) {
            asm volatile("s_waitcnt lgkmcnt(0)" ::: "memory");
            __builtin_amdgcn_s_barrier();        // B2: reads done; nxt may be overwritten
            asm volatile("" ::: "memory");
        }

        __builtin_amdgcn_s_setprio(1);
        f32x4 P[4];
#pragma unroll
        for (int s4 = 0; s4 < 4; ++s4)
#pragma unroll
            for (int sub = 0; sub < 4; ++sub) {
                U8 a; a.u = h1r[sub][s4];
                P[sub] = __builtin_amdgcn_mfma_f32_16x16x32_bf16(
                    a.b, bv[s4].b, (s4 == 0) ? z4 : P[sub], 0, 0, 0);
            }
        __builtin_amdgcn_s_setprio(0);
        SCALE(P, cc);
    }

    {   // bias half-sum for THIS kh: A = out[src] rows (svT), B = be2 frag (sb=kh, ntg)
        U8 bvb;
        bvb.u = *(const u16x8*)(WtF + WTF_BIAS + ((kh * 4 + ntg) * 64 + lane) * 8);
#pragma unroll
        for (int sub = 0; sub < 4; ++sub) {
            int m = w64 + sub * 16 + r16;
            U8 a;
#pragma unroll
            for (int j = 0; j < 8; ++j) {
                int cl = q * 8 + j;              // cl>>3 = q (const per lane)
                a.u[j] = svT[cl * 256 + (m ^ (q << 4))];
            }
            acc[sub] = __builtin_amdgcn_mfma_f32_16x16x32_bf16(
                a.b, bvb.b, acc[sub], 0, 0, 0);
        }
    }

    // scatter-reduce: merge same-dst runs in each lane's 4 rows, atomicAdd into agg
#pragma unroll
    for (int sub = 0; sub < 4; ++sub) {
        int eb = eb0 + w64 + sub * 16 + q * 4;
        if (eb >= NE) continue;
        int d0 = dsts[eb];
        int d1 = (eb + 1 < NE) ? dsts[eb + 1] : -1;
        int d2 = (eb + 2 < NE) ? dsts[eb + 2] : -1;
        int d3 = (eb + 3 < NE) ? dsts[eb + 3] : -1;
        float* base = agg + ntg * 16 + r16;
        float run = acc[sub][0];
        int dp = d0;
        if (d1 == dp) run += acc[sub][1];
        else { atomicAdd(base + (size_t)dp * 64, run); dp = d1; run = acc[sub][1]; }
        if (d2 == dp) run += acc[sub][2];
        else { if (dp >= 0) atomicAdd(base + (size_t)dp * 64, run); dp = d2; run = acc[sub][2]; }
        if (d3 == dp) run += acc[sub][3];
        else { if (dp >= 0) atomicAdd(base + (size_t)dp * 64, run); dp = d3; run = acc[sub][3]; }
        if (dp >= 0) atomicAdd(base + (size_t)dp * 64, run);
    }
}

// -------- GRU: agg read (pre-reduced by k_msg atomics) + MFMA gate GEMM ---------
// C[64x256] = [m|h][64x128] @ WgF[128x256]; gate combine in C-layout registers.
// rezero=0 on the LAST iteration skips the 5.12MB agg re-zero store stream
// (the launcher's memset re-arms agg for the next harness run).
__global__ __launch_bounds__(256) void k_gru(float* __restrict__ h, u16* __restrict__ outb,
    float* __restrict__ agg, const int* __restrict__ rowptr,
    const float* __restrict__ b_conv, const u16* __restrict__ WgF,
    const float* __restrict__ b_ih, const float* __restrict__ b_hh, int rezero)
{
    __shared__ __align__(16) u16 zA[64 * 132];   // [m|h] bf16, row pad 132
    __shared__ float hS[64 * 65];                // old h fp32, row pad 65
    const int t = threadIdx.x;
    const int lane = t & 63, w = t >> 6, r16 = lane & 15, q = lane >> 4;
    const int n0 = blockIdx.x * 64;
    const int w16 = w * 16;
    float bcv = b_conv[lane];

    // ---- phase 1: per-node finish (mean + bias + relu), lane = dim ----
#pragma unroll 4
    for (int p = 0; p < 16; ++p) {
        int n = n0 + w16 + p;
        float m = 0.f, hvv = 0.f;
        if (n < NN) {
            float av = agg[(size_t)n * 64 + lane];
            if (rezero) agg[(size_t)n * 64 + lane] = 0.f;   // re-arm for next iter
            float deg = fmaxf((float)(rowptr[n + 1] - rowptr[n]), 1.f);
            m = fmaxf(av / deg + bcv, 0.f);
            hvv = h[n * 64 + lane];
        }
        zA[(w16 + p) * 132 + lane] = f2bf(m);
        zA[(w16 + p) * 132 + 64 + lane] = f2bf(hvv);
        hS[(w16 + p) * 65 + lane] = hvv;
    }
    // wave-private LDS rows: no cross-wave dependency, no barrier needed

    // ---- phase 2: GEMM, wave computes its 16 nodes x 256 outputs ----
    u16x8 afr[4];
#pragma unroll
    for (int ks = 0; ks < 4; ++ks)
        afr[ks] = *(const u16x8*)&zA[(w16 + r16) * 132 + ks * 32 + q * 8];

    f32x4 acc[16];
    const f32x4 z4 = {0.f, 0.f, 0.f, 0.f};
#pragma unroll
    for (int nt = 0; nt < 16; ++nt) acc[nt] = z4;

    U8 bA[4], bB[4];
    auto LDB = [&](U8* dst, int nt) {
#pragma unroll
        for (int ks = 0; ks < 4; ++ks)
            dst[ks].u = *(const u16x8*)(WgF + ((ks * 16 + nt) * 64 + lane) * 8);
    };
    LDB(bA, 0);
#pragma unroll
    for (int nt = 0; nt < 16; ++nt) {
        U8* cur = (nt & 1) ? bB : bA;
        U8* nxt = (nt & 1) ? bA : bB;
        if (nt < 15) LDB(nxt, nt + 1);
        f32x4 c = acc[nt];
#pragma unroll
        for (int ks = 0; ks < 4; ++ks) {
            U8 a; a.u = afr[ks];
            c = __builtin_amdgcn_mfma_f32_16x16x32_bf16(a.b, cur[ks].b, c, 0, 0, 0);
        }
        acc[nt] = c;
    }

    // ---- phase 3: gate combine; C row = q*4+reg, col = nt*16+r16 ----
#pragma unroll
    for (int reg = 0; reg < 4; ++reg) {
        int nl = w16 + q * 4 + reg;
        int n = n0 + nl;
        if (n >= NN) continue;
#pragma unroll
        for (int dd = 0; dd < 4; ++dd) {
            int d = dd * 16 + r16;
            float rv = acc[dd][reg]      + b_ih[d]       + b_hh[d];
            float zv = acc[4 + dd][reg]  + b_ih[64 + d]  + b_hh[64 + d];
            float iv = acc[8 + dd][reg]  + b_ih[128 + d];
            float hg = acc[12 + dd][reg] + b_hh[128 + d];
            float rr = sigmoidf(rv), zz = sigmoidf(zv);
            float nn = tanhf(iv + rr * hg);
            float hold = hS[nl * 65 + d];
            float hnew = (1.f - zz) * nn + zz * hold;
            h[n * 64 + d] = hnew;
            outb[n * 64 + d] = f2bf(hnew);
        }
    }
}

// -------- fused Set2Set: 1 graph per block, 3x(LSTM + attention) + readout ------
__global__ __launch_bounds__(256) void k_s2s(const float* __restrict__ h,
    const int* __restrict__ gstart, const int* __restrict__ gend,
    const float* __restrict__ WTihl, const float* __restrict__ WThhl,
    const float* __restrict__ b_ihl, const float* __restrict__ b_hhl,
    const float* __restrict__ WT1, const float* __restrict__ b1,
    const float* __restrict__ W2, const float* __restrict__ b2,
    float* __restrict__ outp)
{
    __shared__ float qs[128];        // q_star for this graph
    __shared__ float hlL[64], clL[64];
    __shared__ float gt[256];
    __shared__ float sm[4], sl[4], sr[4][64];
    const int g = blockIdx.x;
    const int t = threadIdx.x, w = t >> 6, lane = t & 63;
    const int s = gstart[g], e = gend[g];

    if (t < 128) qs[t] = 0.f;
    if (t < 64) { hlL[t] = 0.f; clL[t] = 0.f; }
    __syncthreads();

    for (int step = 0; step < 3; ++step) {
        float ga = b_ihl[t] + b_hhl[t];
#pragma unroll 4
        for (int j = 0; j < 128; ++j)
            ga += qs[j] * WTihl[j * 256 + t];
#pragma unroll 4
        for (int j = 0; j < 64; ++j)
            ga += hlL[j] * WThhl[j * 256 + t];
        gt[t] = ga;
        __syncthreads();
        if (t < 64) {
            float cv = sigmoidf(gt[64 + t]) * clL[t] + sigmoidf(gt[t]) * tanhf(gt[128 + t]);
            float hn = sigmoidf(gt[192 + t]) * tanhf(cv);
            clL[t] = cv; hlL[t] = hn; qs[t] = hn;
        }
        __syncthreads();
        float qv = hlL[lane];
        float M = -3.4e38f, l = 0.f, r = 0.f;
        for (int n = s + w; n < e; n += 4) {
            float hvv = h[n * 64 + lane];
            float p = hvv * qv;
#pragma unroll
            for (int off = 32; off > 0; off >>= 1) p += __shfl_xor(p, off, 64);
            if (p > M) {
                float sc = __expf(M - p);
                l = l * sc + 1.f;
                r = r * sc + hvv;
                M = p;
            } else {
                float pe = __expf(p - M);
                l += pe;
                r += pe * hvv;
            }
        }
        if (lane == 0) { sm[w] = M; sl[w] = l; }
        sr[w][lane] = r;
        __syncthreads();
        if (w == 0) {
            float Mg = fmaxf(fmaxf(sm[0], sm[1]), fmaxf(sm[2], sm[3]));
            float lg = 0.f, rg = 0.f;
#pragma unroll
            for (int wp = 0; wp < 4; ++wp) {
                float sc = __expf(sm[wp] - Mg);
                lg += sl[wp] * sc;
                rg += sr[wp][lane] * sc;
            }
            float inv = (lg > 0.f) ? 1.f / lg : 0.f;
            qs[64 + lane] = rg * inv;
        }
        __syncthreads();
    }
    float acc = 0.f;
#pragma unroll 4
    for (int j = w * 32; j < w * 32 + 32; ++j)
        acc += qs[j] * WT1[j * 64 + lane];
    sr[w][lane] = acc;
    __syncthreads();
    if (w == 0) {
        float y = sr[0][lane] + sr[1][lane] + sr[2][lane] + sr[3][lane] + b1[lane];
        float pr = fmaxf(y, 0.f) * W2[lane];
#pragma unroll
        for (int off = 32; off > 0; off >>= 1) pr += __shfl_xor(pr, off, 64);
        if (lane == 0) outp[g] = pr + b2[0];
    }
}

extern "C" void kernel_launch(void* const* d_in, const int* in_sizes, int n_in,
                              void* d_out, int out_size, void* d_ws, size_t ws_size,
                              hipStream_t stream)
{
    const float* x      = (const float*)d_in[0];
    const float* ea     = (const float*)d_in[1];
    const int*   ei     = (const int*)d_in[2];
    const int*   batch  = (const int*)d_in[3];
    const float* W0     = (const float*)d_in[4];
    const float* b0     = (const float*)d_in[5];
    const float* We1    = (const float*)d_in[6];
    const float* be1    = (const float*)d_in[7];
    const float* We2    = (const float*)d_in[8];
    const float* be2    = (const float*)d_in[9];
    const float* b_conv = (const float*)d_in[10];
    const float* W_ih   = (const float*)d_in[11];
    const float* W_hh   = (const float*)d_in[12];
    const float* b_ih   = (const float*)d_in[13];
    const float* b_hh   = (const float*)d_in[14];
    const float* W_ihl  = (const float*)d_in[15];
    const float* W_hhl  = (const float*)d_in[16];
    const float* b_ihl  = (const float*)d_in[17];
    const float* b_hhl  = (const float*)d_in[18];
    const float* W1     = (const float*)d_in[19];
    const float* b1     = (const float*)d_in[20];
    const float* W2     = (const float*)d_in[21];
    const float* b2     = (const float*)d_in[22];
    float* outp = (float*)d_out;

    char* ws = (char*)d_ws;
    size_t off = 0;
    auto alloc = [&](size_t bytes) -> char* {
        char* p = ws + off;
        off += (bytes + 255) & ~(size_t)255;
        return p;
    };
    u16*   h1     = (u16*)  alloc((size_t)NE * 128 * 2);       // 10.24 MB (sorted)
    u16*   WtF    = (u16*)  alloc((WTF_BIAS + 4096) * 2);      // 1.06 MB
    u16*   outb   = (u16*)  alloc((size_t)NN * 64 * 2);        // 2.56 MB
    float* h      = (float*)alloc((size_t)NN * 64 * 4);        // 5.12 MB
    int*   rowptr = (int*)  alloc((NN + 1) * 4);
    int*   epos   = (int*)  alloc(NE * 4);
    int*   srcs   = (int*)  alloc(NE * 4);
    int*   dsts   = (int*)  alloc(NE * 4);
    int*   cnt    = (int*)  alloc(NN * 4);     // cnt..agg contiguous, one memset
    int*   cur    = (int*)  alloc(NN * 4);
    int*   gstart = (int*)  alloc(NGR * 4);
    int*   gend   = (int*)  alloc(NGR * 4);
    float* agg    = (float*)alloc((size_t)NN * 64 * 4);        // 5.12 MB f32
    u16*   WgF    = (u16*)  alloc(32768 * 2);  // frag-major GRU gate weights
    float* WTihl  = (float*)alloc(32768 * 4);
    float* WThhl  = (float*)alloc(16384 * 4);
    float* WT1    = (float*)alloc(8192 * 4);
    if (off > ws_size) return;   // ~26 MB needed

    size_t zspan = (size_t)((char*)(agg + (size_t)NN * 64) - (char*)cnt);
    hipMemsetAsync(cnt, 0, zspan, stream);

    k_cnt<<<64, 256, 0, stream>>>(ei, cnt);
    k_scan<<<1, 1024, 0, stream>>>(cnt, rowptr);
    k_scatter<<<64, 256, 0, stream>>>(ei, rowptr, cur, epos, srcs, dsts);
    k_pre<<<992, 256, 0, stream>>>(x, ea, batch, epos, W0, b0, We1, be1, We2, be2,
                                   W_ih, W_hh, W_ihl, W_hhl, W1,
                                   h, outb, h1, WtF, gstart, gend,
                                   WgF, WTihl, WThhl, WT1);

    dim3 mgrid((NE + 255) / 256, KH, 4);
    for (int it = 0; it < 3; ++it) {
        k_msg<<<mgrid, 256, 0, stream>>>(outb, h1, WtF, srcs, dsts, agg);
        k_gru<<<313, 256, 0, stream>>>(h, outb, agg, rowptr, b_conv,
                                       WgF, b_ih, b_hh, (it < 2) ? 1 : 0);
    }
    k_s2s<<<NGR, 256, 0, stream>>>(h, gstart, gend, WTihl, WThhl, b_ihl, b_hhl,
                                   WT1, b1, W2, b2, outp);
}

// Round 13
// 381.685 us; speedup vs baseline: 1.1399x; 1.1399x over previous
//
#include <hip/hip_runtime.h>

#define NN 20000
#define NE 40000
#define NGR 1000
#define KH 2                      // K-split for k_msg
#define WTF_BIAS 524288           // u16 offset of bias frags in WtF

typedef unsigned short u16;
typedef u16 u16x8 __attribute__((ext_vector_type(8)));
typedef __bf16 bf16x8 __attribute__((ext_vector_type(8)));
typedef float f32x4 __attribute__((ext_vector_type(4)));

union U8 { u16x8 u; bf16x8 b; };

__device__ __forceinline__ u16 f2bf(float f) {
    union { float f; unsigned u; } v; v.f = f;
    unsigned r = v.u + 0x7FFF + ((v.u >> 16) & 1);   // RNE
    return (u16)(r >> 16);
}
__device__ __forceinline__ float bf2f(u16 h) {
    union { unsigned u; float f; } v; v.u = ((unsigned)h) << 16;
    return v.f;
}
__device__ __forceinline__ float sigmoidf(float x) { return 1.f / (1.f + __expf(-x)); }

// async global->LDS, 16B per lane; LDS dest = wave-uniform base + lane*16
__device__ __forceinline__ void gl_lds16(const u16* g, u16* l) {
    __builtin_amdgcn_global_load_lds(
        (const __attribute__((address_space(1))) void*)g,
        (__attribute__((address_space(3))) void*)l, 16, 0, 0);
}

// ---------------- degree count ----------------
__global__ __launch_bounds__(256) void k_cnt(const int* __restrict__ ei, int* __restrict__ cnt)
{
    for (int e = blockIdx.x * 256 + threadIdx.x; e < NE; e += gridDim.x * 256)
        atomicAdd(&cnt[ei[NE + e]], 1);
}

// ---------------- exclusive prefix over cnt -> rowptr[NN+1], one block ----------
__global__ __launch_bounds__(1024) void k_scan(const int* __restrict__ cnt,
                                               int* __restrict__ rowptr)
{
    __shared__ int ps[1024];
    int t = threadIdx.x;
    int base = t * 20;
    int loc[20];
    int s = 0;
#pragma unroll
    for (int i = 0; i < 20; ++i) {
        int idx = base + i;
        loc[i] = s;
        s += (idx < NN) ? cnt[idx] : 0;
    }
    ps[t] = s;
    __syncthreads();
    for (int off = 1; off < 1024; off <<= 1) {
        int v = (t >= off) ? ps[t - off] : 0;
        __syncthreads();
        ps[t] += v;
        __syncthreads();
    }
    int ex = (t > 0) ? ps[t - 1] : 0;
#pragma unroll
    for (int i = 0; i < 20; ++i) {
        int idx = base + i;
        if (idx < NN) rowptr[idx] = ex + loc[i];
    }
    if (t == 1023) rowptr[NN] = ps[1023];
}

// -------- scatter: epos[e] = dst-sorted slot; srcs/dsts[slot] ------------------
__global__ __launch_bounds__(256) void k_scatter(const int* __restrict__ ei,
    const int* __restrict__ rowptr, int* __restrict__ cur,
    int* __restrict__ epos, int* __restrict__ srcs, int* __restrict__ dsts)
{
    for (int e = blockIdx.x * 256 + threadIdx.x; e < NE; e += gridDim.x * 256) {
        int d = ei[NE + e];
        int pos = rowptr[d] + atomicAdd(&cur[d], 1);
        epos[e] = pos;
        srcs[pos] = ei[e];
        dsts[pos] = d;
    }
}

// ============ fused one-time preamble, 992 blocks, role by blockIdx range ======
__global__ __launch_bounds__(256) void k_pre(
    const float* __restrict__ x, const float* __restrict__ ea,
    const int* __restrict__ batch, const int* __restrict__ epos,
    const float* __restrict__ W0, const float* __restrict__ b0,
    const float* __restrict__ We1, const float* __restrict__ be1,
    const float* __restrict__ We2, const float* __restrict__ be2,
    const float* __restrict__ W_ih, const float* __restrict__ W_hh,
    const float* __restrict__ W_ihl, const float* __restrict__ W_hhl,
    const float* __restrict__ W1,
    float* __restrict__ h, u16* __restrict__ outb, u16* __restrict__ h1,
    u16* __restrict__ WtF, int* __restrict__ gstart, int* __restrict__ gend,
    u16* __restrict__ WgF,
    float* __restrict__ WTihl, float* __restrict__ WThhl, float* __restrict__ WT1)
{
    const int b = blockIdx.x;
    const int t = threadIdx.x;

    if (b < 64) {                 // WgF frag-major GRU weights + transposes (90112)
        for (int idx = b * 256 + t; idx < 90112; idx += 64 * 256) {
            int i = idx;
            if (i < 32768) {      // WgF: [ks 0..3][nt 0..15][lane 0..63][j 0..7]
                int j = i & 7, lane = (i >> 3) & 63;
                int nt = (i >> 9) & 15, ks = i >> 13;
                int o = nt * 16 + (lane & 15);
                int k = ks * 32 + (lane >> 4) * 8 + j;
                float v;
                if (o < 128)      v = (k < 64) ? W_ih[o * 64 + k] : W_hh[o * 64 + k - 64];
                else if (o < 192) v = (k < 64) ? W_ih[o * 64 + k] : 0.f;
                else              v = (k >= 64) ? W_hh[(o - 64) * 64 + k - 64] : 0.f;
                WgF[i] = f2bf(v);
                continue;
            }
            i -= 32768;
            if (i < 32768) { WTihl[i] = W_ihl[(i % 256) * 128 + i / 256]; continue; }
            i -= 32768;
            if (i < 16384) { WThhl[i] = W_hhl[(i % 256) * 64 + i / 256]; continue; }
            i -= 16384;
            WT1[i] = W1[(i % 64) * 128 + i / 64];
        }
        return;
    }
    if (b < 320) {                                   // lin0, 1024 waves grid-stride
        int wv = (b - 64) * 4 + (t >> 6);
        int lane = t & 63;
        float w0r[32];
#pragma unroll
        for (int f = 0; f < 32; ++f) w0r[f] = W0[lane * 32 + f];
        float b0v = b0[lane];
        for (int n = wv; n < NN; n += 1024) {
            float xv = (lane < 32) ? x[n * 32 + lane] : 0.f;
            float acc = b0v;
#pragma unroll
            for (int f = 0; f < 32; ++f) acc += __shfl(xv, f, 64) * w0r[f];
            float rv = fmaxf(acc, 0.f);
            h[n * 64 + lane] = rv;
            outb[n * 64 + lane] = f2bf(rv);
        }
        return;
    }
    if (b < 832) {                                   // edge MLP -> dst-sorted h1
        for (int idx = (b - 320) * 256 + t; idx < NE * 128; idx += 512 * 256) {
            int e = idx >> 7, k = idx & 127;
            float acc = be1[k];
#pragma unroll
            for (int j = 0; j < 5; ++j)
                acc += ea[e * 5 + j] * We1[k * 5 + j];
            h1[(size_t)epos[e] * 128 + k] = f2bf(fmaxf(acc, 0.f));
        }
        return;
    }
    if (b < 960) {                                   // WtF: frag-major B for k_msg
        for (int idx = (b - 832) * 256 + t; idx < WTF_BIAS + 4096; idx += 128 * 256) {
            float v;
            if (idx < WTF_BIAS) {
                int j = idx & 7, lane = (idx >> 3) & 63;
                int nt = (idx >> 9) & 3, s4 = (idx >> 11) & 3, ch = idx >> 13;
                int o = nt * 16 + (lane & 15);
                int k = s4 * 32 + (lane >> 4) * 8 + j;
                v = We2[(size_t)(ch * 64 + o) * 128 + k];
            } else {
                int bx = idx - WTF_BIAS;
                int j = bx & 7, lane = (bx >> 3) & 63;
                int nt = (bx >> 9) & 3, sb = bx >> 11;
                int o = nt * 16 + (lane & 15);
                int i = sb * 32 + (lane >> 4) * 8 + j;
                v = be2[i * 64 + o];
            }
            WtF[idx] = f2bf(v);
        }
        return;
    }
    {                                                // graph ranges (batch sorted)
        for (int idx = (b - 960) * 256 + t; idx < NN; idx += 32 * 256) {
            int bg = batch[idx];
            if (idx == 0 || batch[idx - 1] != bg) gstart[bg] = idx;
            if (idx == NN - 1 || batch[idx + 1] != bg) gend[bg] = idx + 1;
        }
    }
}

// ---------------- message GEMM + fused scatter-reduce -----------------------------
// R13 = revert to R11, the best measured configuration (52.0 us k_msg, 382.8 us
// total). The full exploration matrix is closed: R12's z=4 split regressed
// (h1 HBM traffic doubled, barrier rate doubled); R6/R7 fatter phases lost
// occupancy; R8 hard drains serialized the stage; R3-R5 fixed all supply-side
// counters. R11 = R9's counted-vmcnt dual-barrier schedule + 16KB kh-local svT.
__global__ __launch_bounds__(256, 3) void k_msg(
    const u16* __restrict__ outb, const u16* __restrict__ h1,
    const u16* __restrict__ WtF, const int* __restrict__ srcs,
    const int* __restrict__ dsts, float* __restrict__ agg)
{
    __shared__ __align__(16) u16 svT[32 * 256];  // [cl][row ^ ((cl>>3)<<4)], 16 KB
    __shared__ __align__(16) u16 LB[2 * 4096];   // B stage, 2 x (8 frags x 512 u16)
    const int t = threadIdx.x;
    const int eb0 = blockIdx.x * 256;
    const int kh = blockIdx.y;                   // channel half: ch = kh*32 + cl
    const int ohc = (int)blockIdx.z * 2;         // output half: ntg = ohc + nt

#pragma unroll
    for (int r = 0; r < 4; ++r) {                // gather out[srcs] kh-half -> svT
        int cid = t + 256 * r;                   // 0..1023
        int row = cid >> 2, c4 = cid & 3;        // 256 rows x 4 chunks of 8 dims
        int e = eb0 + row;
        u16x8 v = {};
        if (e < NE) {
            int s = srcs[e];
            v = *(const u16x8*)(outb + (size_t)s * 64 + kh * 32 + c4 * 8);
        }
        int rs = row ^ (c4 << 4);                // swz = (cl>>3)<<4, cl = c4*8+j
#pragma unroll
        for (int j = 0; j < 8; ++j)
            svT[(c4 * 8 + j) * 256 + rs] = v[j];
    }

    const int lane = t & 63, w = t >> 6, r16 = lane & 15, q = lane >> 4;
    const int w64 = w * 64;

    // static A-fragments: h1 rows, 64 edges/wave, reused across all channels
    u16x8 h1r[4][4];
#pragma unroll
    for (int sub = 0; sub < 4; ++sub) {
        int e = eb0 + w64 + sub * 16 + r16;
        if (e >= NE) e = NE - 1;                 // contribution zeroed via sv=0
        const u16* hp = h1 + (size_t)e * 128 + q * 8;
#pragma unroll
        for (int s4 = 0; s4 < 4; ++s4)
            h1r[sub][s4] = *(const u16x8*)(hp + s4 * 32);
    }

    f32x4 acc[4][2];
    const f32x4 z4 = {0.f, 0.f, 0.f, 0.f};
#pragma unroll
    for (int sub = 0; sub < 4; ++sub)
#pragma unroll
        for (int nt = 0; nt < 2; ++nt) acc[sub][nt] = z4;

    const int chBase = kh * 32;
    u16* lb0 = &LB[0];
    u16* lb1 = &LB[4096];

    // stage channel ch's B-quarter (8 frags x 1KB) into lb; wave w does frags 2w,2w+1
    auto STAGE = [&](u16* lb, int ch) {
        const u16* g = WtF + (size_t)ch * 8192 + w * 2048 + ohc * 512 + lane * 8;
        gl_lds16(g,       lb + (2 * w) * 512);
        gl_lds16(g + 512, lb + (2 * w + 1) * 512);
    };
    auto SCALE = [&](f32x4 (&P)[4][2], int cl) {   // cl = local channel [0,32)
        int swz = (cl >> 3) << 4;
#pragma unroll
        for (int sub = 0; sub < 4; ++sub) {
            int mb = (w64 + sub * 16 + q * 4) ^ swz;
            uint2 rv = *(const uint2*)&svT[cl * 256 + mb];
            union { unsigned u; float f; } c0, c1, c2, c3;
            c0.u = rv.x << 16; c1.u = rv.x & 0xffff0000u;
            c2.u = rv.y << 16; c3.u = rv.y & 0xffff0000u;
#pragma unroll
            for (int nt = 0; nt < 2; ++nt) {
                acc[sub][nt][0] += c0.f * P[sub][nt][0];
                acc[sub][nt][1] += c1.f * P[sub][nt][1];
                acc[sub][nt][2] += c2.f * P[sub][nt][2];
                acc[sub][nt][3] += c3.f * P[sub][nt][3];
            }
        }
    };

    STAGE(lb0, chBase);                          // prefetch channel 0

#pragma unroll 1
    for (int cc = 0; cc < 32; ++cc) {
        u16* cur = (cc & 1) ? lb1 : lb0;
        u16* nxt = (cc & 1) ? lb0 : lb1;
        if (cc < 31) {
            STAGE(nxt, chBase + cc + 1);         // issue next-channel loads
            // cur's 2 stage loads (older) must land; the 2 just-issued stay in flight
            asm volatile("s_waitcnt vmcnt(2) lgkmcnt(0)" ::: "memory");
        } else {
            asm volatile("s_waitcnt vmcnt(0) lgkmcnt(0)" ::: "memory");
        }
        __builtin_amdgcn_s_barrier();            // B1: cur buffer fully written
        asm volatile("" ::: "memory");

        U8 bv[8];                                // shared B frags: LDS -> regs
#pragma unroll
        for (int f = 0; f < 8; ++f)
            bv[f].u = *(const u16x8*)(cur + f * 512 + lane * 8);

        if (cc < 31) {
            asm volatile("s_waitcnt lgkmcnt(0)" ::: "memory");
            __builtin_amdgcn_s_barrier();        // B2: reads done; nxt may be overwritten
            asm volatile("" ::: "memory");
        }

        __builtin_amdgcn_s_setprio(1);
        f32x4 P[4][2];
#pragma unroll
        for (int s4 = 0; s4 < 4; ++s4)
#pragma unroll
            for (int sub = 0; sub < 4; ++sub) {
                U8 a; a.u = h1r[sub][s4];
#pragma unroll
                for (int nt = 0; nt < 2; ++nt)
                    P[sub][nt] = __builtin_amdgcn_mfma_f32_16x16x32_bf16(
                        a.b, bv[s4 * 2 + nt].b, (s4 == 0) ? z4 : P[sub][nt], 0, 0, 0);
            }
        __builtin_amdgcn_s_setprio(0);
        SCALE(P, cc);
    }

    {   // bias half-sum for THIS kh: A = out[src] rows (svT), B = be2 frags sb=kh
        U8 bvb[2];
#pragma unroll
        for (int nt = 0; nt < 2; ++nt)
            bvb[nt].u = *(const u16x8*)(WtF + WTF_BIAS +
                                        ((kh * 4 + ohc + nt) * 64 + lane) * 8);
#pragma unroll
        for (int sub = 0; sub < 4; ++sub) {
            int m = w64 + sub * 16 + r16;
            U8 a;
#pragma unroll
            for (int j = 0; j < 8; ++j) {
                int cl = q * 8 + j;              // cl>>3 = q (const per lane)
                a.u[j] = svT[cl * 256 + (m ^ (q << 4))];
            }
#pragma unroll
            for (int nt = 0; nt < 2; ++nt)
                acc[sub][nt] = __builtin_amdgcn_mfma_f32_16x16x32_bf16(
                    a.b, bvb[nt].b, acc[sub][nt], 0, 0, 0);
        }
    }

    // scatter-reduce: merge same-dst runs in each lane's 4 rows, atomicAdd into agg
#pragma unroll
    for (int sub = 0; sub < 4; ++sub) {
        int eb = eb0 + w64 + sub * 16 + q * 4;
        if (eb >= NE) continue;
        int d0 = dsts[eb];
        int d1 = (eb + 1 < NE) ? dsts[eb + 1] : -1;
        int d2 = (eb + 2 < NE) ? dsts[eb + 2] : -1;
        int d3 = (eb + 3 < NE) ? dsts[eb + 3] : -1;
#pragma unroll
        for (int nt = 0; nt < 2; ++nt) {
            float* base = agg + (ohc + nt) * 16 + r16;
            float run = acc[sub][nt][0];
            int dp = d0;
            if (d1 == dp) run += acc[sub][nt][1];
            else { atomicAdd(base + (size_t)dp * 64, run); dp = d1; run = acc[sub][nt][1]; }
            if (d2 == dp) run += acc[sub][nt][2];
            else { if (dp >= 0) atomicAdd(base + (size_t)dp * 64, run); dp = d2; run = acc[sub][nt][2]; }
            if (d3 == dp) run += acc[sub][nt][3];
            else { if (dp >= 0) atomicAdd(base + (size_t)dp * 64, run); dp = d3; run = acc[sub][nt][3]; }
            if (dp >= 0) atomicAdd(base + (size_t)dp * 64, run);
        }
    }
}

// -------- GRU: agg read (pre-reduced by k_msg atomics) + MFMA gate GEMM ---------
// C[64x256] = [m|h][64x128] @ WgF[128x256]; gate combine in C-layout registers.
// rezero=0 on the LAST iteration skips the 5.12MB agg re-zero store stream
// (the launcher's memset re-arms agg for the next harness run).
__global__ __launch_bounds__(256) void k_gru(float* __restrict__ h, u16* __restrict__ outb,
    float* __restrict__ agg, const int* __restrict__ rowptr,
    const float* __restrict__ b_conv, const u16* __restrict__ WgF,
    const float* __restrict__ b_ih, const float* __restrict__ b_hh, int rezero)
{
    __shared__ __align__(16) u16 zA[64 * 132];   // [m|h] bf16, row pad 132
    __shared__ float hS[64 * 65];                // old h fp32, row pad 65
    const int t = threadIdx.x;
    const int lane = t & 63, w = t >> 6, r16 = lane & 15, q = lane >> 4;
    const int n0 = blockIdx.x * 64;
    const int w16 = w * 16;
    float bcv = b_conv[lane];

    // ---- phase 1: per-node finish (mean + bias + relu), lane = dim ----
#pragma unroll 4
    for (int p = 0; p < 16; ++p) {
        int n = n0 + w16 + p;
        float m = 0.f, hvv = 0.f;
        if (n < NN) {
            float av = agg[(size_t)n * 64 + lane];
            if (rezero) agg[(size_t)n * 64 + lane] = 0.f;   // re-arm for next iter
            float deg = fmaxf((float)(rowptr[n + 1] - rowptr[n]), 1.f);
            m = fmaxf(av / deg + bcv, 0.f);
            hvv = h[n * 64 + lane];
        }
        zA[(w16 + p) * 132 + lane] = f2bf(m);
        zA[(w16 + p) * 132 + 64 + lane] = f2bf(hvv);
        hS[(w16 + p) * 65 + lane] = hvv;
    }
    // wave-private LDS rows: no cross-wave dependency, no barrier needed

    // ---- phase 2: GEMM, wave computes its 16 nodes x 256 outputs ----
    u16x8 afr[4];
#pragma unroll
    for (int ks = 0; ks < 4; ++ks)
        afr[ks] = *(const u16x8*)&zA[(w16 + r16) * 132 + ks * 32 + q * 8];

    f32x4 acc[16];
    const f32x4 z4 = {0.f, 0.f, 0.f, 0.f};
#pragma unroll
    for (int nt = 0; nt < 16; ++nt) acc[nt] = z4;

    U8 bA[4], bB[4];
    auto LDB = [&](U8* dst, int nt) {
#pragma unroll
        for (int ks = 0; ks < 4; ++ks)
            dst[ks].u = *(const u16x8*)(WgF + ((ks * 16 + nt) * 64 + lane) * 8);
    };
    LDB(bA, 0);
#pragma unroll
    for (int nt = 0; nt < 16; ++nt) {
        U8* cur = (nt & 1) ? bB : bA;
        U8* nxt = (nt & 1) ? bA : bB;
        if (nt < 15) LDB(nxt, nt + 1);
        f32x4 c = acc[nt];
#pragma unroll
        for (int ks = 0; ks < 4; ++ks) {
            U8 a; a.u = afr[ks];
            c = __builtin_amdgcn_mfma_f32_16x16x32_bf16(a.b, cur[ks].b, c, 0, 0, 0);
        }
        acc[nt] = c;
    }

    // ---- phase 3: gate combine; C row = q*4+reg, col = nt*16+r16 ----
#pragma unroll
    for (int reg = 0; reg < 4; ++reg) {
        int nl = w16 + q * 4 + reg;
        int n = n0 + nl;
        if (n >= NN) continue;
#pragma unroll
        for (int dd = 0; dd < 4; ++dd) {
            int d = dd * 16 + r16;
            float rv = acc[dd][reg]      + b_ih[d]       + b_hh[d];
            float zv = acc[4 + dd][reg]  + b_ih[64 + d]  + b_hh[64 + d];
            float iv = acc[8 + dd][reg]  + b_ih[128 + d];
            float hg = acc[12 + dd][reg] + b_hh[128 + d];
            float rr = sigmoidf(rv), zz = sigmoidf(zv);
            float nn = tanhf(iv + rr * hg);
            float hold = hS[nl * 65 + d];
            float hnew = (1.f - zz) * nn + zz * hold;
            h[n * 64 + d] = hnew;
            outb[n * 64 + d] = f2bf(hnew);
        }
    }
}

// -------- fused Set2Set: 1 graph per block, 3x(LSTM + attention) + readout ------
__global__ __launch_bounds__(256) void k_s2s(const float* __restrict__ h,
    const int* __restrict__ gstart, const int* __restrict__ gend,
    const float* __restrict__ WTihl, const float* __restrict__ WThhl,
    const float* __restrict__ b_ihl, const float* __restrict__ b_hhl,
    const float* __restrict__ WT1, const float* __restrict__ b1,
    const float* __restrict__ W2, const float* __restrict__ b2,
    float* __restrict__ outp)
{
    __shared__ float qs[128];        // q_star for this graph
    __shared__ float hlL[64], clL[64];
    __shared__ float gt[256];
    __shared__ float sm[4], sl[4], sr[4][64];
    const int g = blockIdx.x;
    const int t = threadIdx.x, w = t >> 6, lane = t & 63;
    const int s = gstart[g], e = gend[g];

    if (t < 128) qs[t] = 0.f;
    if (t < 64) { hlL[t] = 0.f; clL[t] = 0.f; }
    __syncthreads();

    for (int step = 0; step < 3; ++step) {
        float ga = b_ihl[t] + b_hhl[t];
#pragma unroll 4
        for (int j = 0; j < 128; ++j)
            ga += qs[j] * WTihl[j * 256 + t];
#pragma unroll 4
        for (int j = 0; j < 64; ++j)
            ga += hlL[j] * WThhl[j * 256 + t];
        gt[t] = ga;
        __syncthreads();
        if (t < 64) {
            float cv = sigmoidf(gt[64 + t]) * clL[t] + sigmoidf(gt[t]) * tanhf(gt[128 + t]);
            float hn = sigmoidf(gt[192 + t]) * tanhf(cv);
            clL[t] = cv; hlL[t] = hn; qs[t] = hn;
        }
        __syncthreads();
        float qv = hlL[lane];
        float M = -3.4e38f, l = 0.f, r = 0.f;
        for (int n = s + w; n < e; n += 4) {
            float hvv = h[n * 64 + lane];
            float p = hvv * qv;
#pragma unroll
            for (int off = 32; off > 0; off >>= 1) p += __shfl_xor(p, off, 64);
            if (p > M) {
                float sc = __expf(M - p);
                l = l * sc + 1.f;
                r = r * sc + hvv;
                M = p;
            } else {
                float pe = __expf(p - M);
                l += pe;
                r += pe * hvv;
            }
        }
        if (lane == 0) { sm[w] = M; sl[w] = l; }
        sr[w][lane] = r;
        __syncthreads();
        if (w == 0) {
            float Mg = fmaxf(fmaxf(sm[0], sm[1]), fmaxf(sm[2], sm[3]));
            float lg = 0.f, rg = 0.f;
#pragma unroll
            for (int wp = 0; wp < 4; ++wp) {
                float sc = __expf(sm[wp] - Mg);
                lg += sl[wp] * sc;
                rg += sr[wp][lane] * sc;
            }
            float inv = (lg > 0.f) ? 1.f / lg : 0.f;
            qs[64 + lane] = rg * inv;
        }
        __syncthreads();
    }
    float acc = 0.f;
#pragma unroll 4
    for (int j = w * 32; j < w * 32 + 32; ++j)
        acc += qs[j] * WT1[j * 64 + lane];
    sr[w][lane] = acc;
    __syncthreads();
    if (w == 0) {
        float y = sr[0][lane] + sr[1][lane] + sr[2][lane] + sr[3][lane] + b1[lane];
        float pr = fmaxf(y, 0.f) * W2[lane];
#pragma unroll
        for (int off = 32; off > 0; off >>= 1) pr += __shfl_xor(pr, off, 64);
        if (lane == 0) outp[g] = pr + b2[0];
    }
}

extern "C" void kernel_launch(void* const* d_in, const int* in_sizes, int n_in,
                              void* d_out, int out_size, void* d_ws, size_t ws_size,
                              hipStream_t stream)
{
    const float* x      = (const float*)d_in[0];
    const float* ea     = (const float*)d_in[1];
    const int*   ei     = (const int*)d_in[2];
    const int*   batch  = (const int*)d_in[3];
    const float* W0     = (const float*)d_in[4];
    const float* b0     = (const float*)d_in[5];
    const float* We1    = (const float*)d_in[6];
    const float* be1    = (const float*)d_in[7];
    const float* We2    = (const float*)d_in[8];
    const float* be2    = (const float*)d_in[9];
    const float* b_conv = (const float*)d_in[10];
    const float* W_ih   = (const float*)d_in[11];
    const float* W_hh   = (const float*)d_in[12];
    const float* b_ih   = (const float*)d_in[13];
    const float* b_hh   = (const float*)d_in[14];
    const float* W_ihl  = (const float*)d_in[15];
    const float* W_hhl  = (const float*)d_in[16];
    const float* b_ihl  = (const float*)d_in[17];
    const float* b_hhl  = (const float*)d_in[18];
    const float* W1     = (const float*)d_in[19];
    const float* b1     = (const float*)d_in[20];
    const float* W2     = (const float*)d_in[21];
    const float* b2     = (const float*)d_in[22];
    float* outp = (float*)d_out;

    char* ws = (char*)d_ws;
    size_t off = 0;
    auto alloc = [&](size_t bytes) -> char* {
        char* p = ws + off;
        off += (bytes + 255) & ~(size_t)255;
        return p;
    };
    u16*   h1     = (u16*)  alloc((size_t)NE * 128 * 2);       // 10.24 MB (sorted)
    u16*   WtF    = (u16*)  alloc((WTF_BIAS + 4096) * 2);      // 1.06 MB
    u16*   outb   = (u16*)  alloc((size_t)NN * 64 * 2);        // 2.56 MB
    float* h      = (float*)alloc((size_t)NN * 64 * 4);        // 5.12 MB
    int*   rowptr = (int*)  alloc((NN + 1) * 4);
    int*   epos   = (int*)  alloc(NE * 4);
    int*   srcs   = (int*)  alloc(NE * 4);
    int*   dsts   = (int*)  alloc(NE * 4);
    int*   cnt    = (int*)  alloc(NN * 4);     // cnt..agg contiguous, one memset
    int*   cur    = (int*)  alloc(NN * 4);
    int*   gstart = (int*)  alloc(NGR * 4);
    int*   gend   = (int*)  alloc(NGR * 4);
    float* agg    = (float*)alloc((size_t)NN * 64 * 4);        // 5.12 MB f32
    u16*   WgF    = (u16*)  alloc(32768 * 2);  // frag-major GRU gate weights
    float* WTihl  = (float*)alloc(32768 * 4);
    float* WThhl  = (float*)alloc(16384 * 4);
    float* WT1    = (float*)alloc(8192 * 4);
    if (off > ws_size) return;   // ~26 MB needed

    size_t zspan = (size_t)((char*)(agg + (size_t)NN * 64) - (char*)cnt);
    hipMemsetAsync(cnt, 0, zspan, stream);

    k_cnt<<<64, 256, 0, stream>>>(ei, cnt);
    k_scan<<<1, 1024, 0, stream>>>(cnt, rowptr);
    k_scatter<<<64, 256, 0, stream>>>(ei, rowptr, cur, epos, srcs, dsts);
    k_pre<<<992, 256, 0, stream>>>(x, ea, batch, epos, W0, b0, We1, be1, We2, be2,
                                   W_ih, W_hh, W_ihl, W_hhl, W1,
                                   h, outb, h1, WtF, gstart, gend,
                                   WgF, WTihl, WThhl, WT1);

    dim3 mgrid((NE + 255) / 256, KH, 2);
    for (int it = 0; it < 3; ++it) {
        k_msg<<<mgrid, 256, 0, stream>>>(outb, h1, WtF, srcs, dsts, agg);
        k_gru<<<313, 256, 0, stream>>>(h, outb, agg, rowptr, b_conv,
                                       WgF, b_ih, b_hh, (it < 2) ? 1 : 0);
    }
    k_s2s<<<NGR, 256, 0, stream>>>(h, gstart, gend, WTihl, WThhl, b_ihl, b_hhl,
                                   WT1, b1, W2, b2, outp);
}